// Round 14
// baseline (131.876 us; speedup 1.0000x reference)
//
#include <hip/hip_runtime.h>

#define SP    65536      // 16*64*64 spatial voxels
#define DD    16
#define HH    64
#define WW    64
#define CIN   64
#define COUT  64

#define XP    132        // proj x-tile pitch (floats)
#define WP    68         // proj w-tile pitch

#define LOG2E 1.44269504f

// ws layout (fp32): q [64][SP] | k [64][SP] | v [64][SP]   (48 MB)
// round-10 lesson: bf16 k fails accuracy (k feeds exp). k stays fp32.
// round-13 lesson: readfirstlane is int(int) — passing float VALUE-converts
// (truncates!). Always bitcast: __int_as_float(rfl(__float_as_int(x))).

__global__ __launch_bounds__(256) void proj(const float* __restrict__ x,
                                            const float* __restrict__ wq,
                                            const float* __restrict__ wk,
                                            const float* __restrict__ wv,
                                            float* __restrict__ q,
                                            float* __restrict__ k,
                                            float* __restrict__ v) {
    __shared__ float xl[CIN][XP];     // [c][p] 33.8 KB
    __shared__ float wl[COUT][WP];    // [o][c] 17.4 KB

    const int t  = threadIdx.x;
    const int p0 = blockIdx.x * 128;
    const int m  = blockIdx.y;

    const float* __restrict__ wsel = (m == 0) ? wq : (m == 1) ? wk : wv;
    float* __restrict__       osel = (m == 0) ? q  : (m == 1) ? k  : v;

#pragma unroll
    for (int i = 0; i < 8; ++i) {
        const int f = t + 256 * i;
        const int c = f >> 5, j = f & 31;
        *(float4*)(&xl[c][j * 4]) = *(const float4*)(x + c * SP + p0 + j * 4);
    }
#pragma unroll
    for (int i = 0; i < 4; ++i) {
        const int f = t + 256 * i;
        const int o = f >> 4, j = f & 15;
        *(float4*)(&wl[o][j * 4]) = *(const float4*)(wsel + o * CIN + j * 4);
    }
    __syncthreads();

    const int og    = t >> 5;        // 0..7
    const int pg    = t & 31;        // 0..31
    const int obase = og * 8;
    const int pbase = pg * 4;

    float acc[8][4] = {};
#pragma unroll 2
    for (int c4 = 0; c4 < CIN / 4; ++c4) {
        float4 w4[8], x4[4];
#pragma unroll
        for (int i = 0; i < 8; ++i)
            w4[i] = *(const float4*)(&wl[obase + i][c4 * 4]);
#pragma unroll
        for (int cc = 0; cc < 4; ++cc)
            x4[cc] = *(const float4*)(&xl[c4 * 4 + cc][pbase]);
#pragma unroll
        for (int i = 0; i < 8; ++i) {
            const float* wf = (const float*)&w4[i];
#pragma unroll
            for (int cc = 0; cc < 4; ++cc) {
                const float* xf = (const float*)&x4[cc];
                const float wv_ = wf[cc];
                acc[i][0] = fmaf(wv_, xf[0], acc[i][0]);
                acc[i][1] = fmaf(wv_, xf[1], acc[i][1]);
                acc[i][2] = fmaf(wv_, xf[2], acc[i][2]);
                acc[i][3] = fmaf(wv_, xf[3], acc[i][3]);
            }
        }
    }

#pragma unroll
    for (int i = 0; i < 8; ++i)
        *(float4*)(osel + (obase + i) * SP + p0 + pbase) =
            make_float4(acc[i][0], acc[i][1], acc[i][2], acc[i][3]);
}

// DPP shifts within 16-lane rows; bound_ctrl=1 -> out-of-row reads 0 =
// exactly the w-boundary zero-pad (wg==0/15 are DPP row boundaries).
__device__ __forceinline__ float dpp_shr1(float x) {   // lane i <- lane i-1
    return __int_as_float(__builtin_amdgcn_mov_dpp(__float_as_int(x), 0x111, 0xf, 0xf, true));
}
__device__ __forceinline__ float dpp_shl1(float x) {   // lane i <- lane i+1
    return __int_as_float(__builtin_amdgcn_mov_dpp(__float_as_int(x), 0x101, 0xf, 0xf, true));
}

__device__ __forceinline__ float b2f(unsigned short u) {
    return __uint_as_float(((unsigned)u) << 16);
}
__device__ __forceinline__ unsigned short f2b(float f) {
    union { float f; unsigned u; } c; c.f = f;
    unsigned r = c.u + 0x7fff + ((c.u >> 16) & 1);   // RNE bf16
    return (unsigned short)(r >> 16);
}
__device__ __forceinline__ float rfl_f(float x) {     // readfirstlane, BITCAST
    return __int_as_float(__builtin_amdgcn_readfirstlane(__float_as_int(x)));
}

// attn v4 (fixed): single unified body; rc27[27] per-tap rel table built
// once per block (axis select folded), scalarized via BITCAST readfirstlane;
// v tile bf16 in LDS (linear path only; k stays fp32): 22.5 KB -> 7
// blocks/CU.
__global__ __launch_bounds__(256) void attn(const float* __restrict__ kbuf,
                                            const float* __restrict__ vbuf,
                                            const float* __restrict__ qbuf,
                                            const float* __restrict__ rel_d,
                                            const float* __restrict__ rel_h,
                                            const float* __restrict__ rel_w,
                                            float* __restrict__ out) {
    __shared__ float          kt[60 * 64];   // [nn][hp][w] fp32, 15 KB
    __shared__ unsigned short vt[60 * 64];   // bf16, 7.5 KB

    const int dt = blockIdx.x;       // 0..3
    const int ht = blockIdx.y;       // 0..7
    const int o  = blockIdx.z;       // 0..63

    const int d0 = dt * 4;
    const int h0 = ht * 8;
    const int t  = threadIdx.x;

    const float* __restrict__ kc = kbuf + o * SP;
    const float* __restrict__ vc = vbuf + o * SP;

    // per-block rel triple + axis
    float r0, r1, r2; int axis;
    if (o < 21)      { axis = 0; r0 = rel_d[o*3+0]; r1 = rel_d[o*3+1]; r2 = rel_d[o*3+2]; }
    else if (o < 42) { axis = 1; const int b = o-21; r0 = rel_h[b*3+0]; r1 = rel_h[b*3+1]; r2 = rel_h[b*3+2]; }
    else             { axis = 2; const int b = o-42; r0 = rel_w[b*3+0]; r1 = rel_w[b*3+1]; r2 = rel_w[b*3+2]; }

    // rc27: per-tap rel, axis select folded once, scalarized (bitcast!)
    float rc27[27];
#pragma unroll
    for (int j = 0; j < 27; ++j) {
        const int kd = j / 9, kh = (j / 3) % 3, kw = j % 3;
        const float ad = (kd == 0) ? r0 : (kd == 1) ? r1 : r2;
        const float ah = (kh == 0) ? r0 : (kh == 1) ? r1 : r2;
        const float aw = (kw == 0) ? r0 : (kw == 1) ? r1 : r2;
        rc27[j] = rfl_f((axis == 0) ? ad : (axis == 1) ? ah : aw);
    }

    // stage: k 960 float4 chunks, v 960 float4->ushort4 chunks
#pragma unroll
    for (int i = 0; i < 8; ++i) {
        const int idx = t + 256 * i;
        if (idx < 1920) {
            const bool isv = idx >= 960;
            const int rem  = isv ? idx - 960 : idx;
            const int row  = rem >> 4;         // 0..59
            const int j    = rem & 15;
            const int nn   = row / 10;
            const int hp   = row - nn * 10;
            const int dpg  = d0 - 1 + nn;
            const int hpg  = h0 - 1 + hp;
            float4 val = make_float4(0.f, 0.f, 0.f, 0.f);
            if ((unsigned)dpg < (unsigned)DD && (unsigned)hpg < (unsigned)HH) {
                const float* src = (isv ? vc : kc) + (dpg * HH + hpg) * WW + j * 4;
                val = *(const float4*)src;
            }
            if (isv) {
                ushort4 st;
                st.x = f2b(val.x); st.y = f2b(val.y); st.z = f2b(val.z); st.w = f2b(val.w);
                *(ushort4*)(vt + row * 64 + j * 4) = st;
            } else {
                *(float4*)(kt + row * 64 + j * 4) = val;
            }
        }
    }

    const int wg = t & 15;           // 4w each
    const int h  = (t >> 4) & 7;
    const int dg = t >> 7;           // 0/1: d-pair

    float ql[2][4];
#pragma unroll
    for (int di = 0; di < 2; ++di) {
        const int dabs = d0 + dg * 2 + di;
        const float4 q4 = *(const float4*)(qbuf + o * SP + (dabs * HH + (h0 + h)) * WW + wg * 4);
        ql[di][0] = q4.x * LOG2E; ql[di][1] = q4.y * LOG2E;
        ql[di][2] = q4.z * LOG2E; ql[di][3] = q4.w * LOG2E;
    }

    __syncthreads();

    float s[2][4] = {};
    float a[2][4] = {};

#pragma unroll
    for (int nl = 0; nl < 4; ++nl) {             // local halo d-row
#pragma unroll
        for (int kh = 0; kh < 3; ++kh) {
            const int rowbase = ((dg * 2 + nl) * 10 + h + kh) * 64 + wg * 4;
            const float4  km = *(const float4*)(kt + rowbase);
            const ushort4 vu = *(const ushort4*)(vt + rowbase);
            const float vf0 = b2f(vu.x), vf1 = b2f(vu.y), vf2 = b2f(vu.z), vf3 = b2f(vu.w);
            const float kl = dpp_shr1(km.w), kr = dpp_shl1(km.x);
            const float vl = dpp_shr1(vf3), vr = dpp_shl1(vf0);
            const float krow[6] = { kl, km.x, km.y, km.z, km.w, kr };
            const float vrow[6] = { vl, vf0, vf1, vf2, vf3, vr };

#pragma unroll
            for (int di = 0; di < 2; ++di) {
                const int kd = nl - di;          // compile-time
                if (kd >= 0 && kd < 3) {
#pragma unroll
                    for (int wi = 0; wi < 4; ++wi) {
                        const float qv = ql[di][wi];
#pragma unroll
                        for (int kw = 0; kw < 3; ++kw) {
                            const float e = __builtin_amdgcn_exp2f(
                                qv * (krow[wi + kw] + rc27[kd * 9 + kh * 3 + kw]));
                            s[di][wi] += e;
                            a[di][wi] = fmaf(e, vrow[wi + kw], a[di][wi]);
                        }
                    }
                }
            }
        }
    }

#pragma unroll
    for (int di = 0; di < 2; ++di) {
        const int dabs = d0 + dg * 2 + di;
        float4 ov;
        ov.x = a[di][0] * __builtin_amdgcn_rcpf(s[di][0]);
        ov.y = a[di][1] * __builtin_amdgcn_rcpf(s[di][1]);
        ov.z = a[di][2] * __builtin_amdgcn_rcpf(s[di][2]);
        ov.w = a[di][3] * __builtin_amdgcn_rcpf(s[di][3]);
        *(float4*)(out + o * SP + (dabs * HH + (h0 + h)) * WW + wg * 4) = ov;
    }
}

extern "C" void kernel_launch(void* const* d_in, const int* in_sizes, int n_in,
                              void* d_out, int out_size, void* d_ws, size_t ws_size,
                              hipStream_t stream) {
    const float* x     = (const float*)d_in[0];
    const float* w_q   = (const float*)d_in[1];
    const float* w_k   = (const float*)d_in[2];
    const float* w_v   = (const float*)d_in[3];
    const float* rel_d = (const float*)d_in[4];
    const float* rel_h = (const float*)d_in[5];
    const float* rel_w = (const float*)d_in[6];
    float* out = (float*)d_out;

    float* ws = (float*)d_ws;
    float* q  = ws;
    float* k  = ws + (size_t)COUT * SP;
    float* v  = ws + 2 * (size_t)COUT * SP;

    proj<<<dim3(SP / 128, 3), 256, 0, stream>>>(x, w_q, w_k, w_v, q, k, v);
    attn<<<dim3(4, 8, 64), 256, 0, stream>>>(k, v, q, rel_d, rel_h, rel_w, out);
}

// Round 15
// 129.178 us; speedup vs baseline: 1.0209x; 1.0209x over previous
//
#include <hip/hip_runtime.h>

#define SP    65536      // 16*64*64 spatial voxels
#define DD    16
#define HH    64
#define WW    64
#define CIN   64
#define COUT  64

#define LOG2E 1.44269504f

#define WPITCH 72        // bf16 LDS pitch (shorts): 144 B rows, 16B-aligned
#define XPITCH 72

typedef short short8 __attribute__((ext_vector_type(8)));
typedef float floatx4 __attribute__((ext_vector_type(4)));

// ws layout (fp32): q [64][SP] | k [64][SP] | v [64][SP]   (48 MB)
// round-10 lesson: bf16 k/v in HBM fails accuracy (k feeds exp; v-bf16 cvt
// cost eats its gain). Intermediates stay fp32.
// round-13 lesson: readfirstlane is int(int) — bitcast floats.

__device__ __forceinline__ float b2f(unsigned short u) {
    return __uint_as_float(((unsigned)u) << 16);
}
__device__ __forceinline__ unsigned short f2b(float f) {
    union { float f; unsigned u; } c; c.f = f;
    unsigned r = c.u + 0x7fff + ((c.u >> 16) & 1);   // RNE bf16
    return (unsigned short)(r >> 16);
}

// proj v5: split-precision bf16 MFMA GEMM. w = w_hi + w_lo, x = x_hi + x_lo
// (RNE bf16); w*x ~ whi*xhi + whi*xlo + wlo*xhi (error ~2^-16 rel — k error
// ~1e-4, safe). Per wave: 16o x 128p, 8 p-tiles x 2 k-steps x 3 terms = 48
// v_mfma_f32_16x16x32_bf16. Layouts (m89/m120-verified): A[m=lane&15]
// [k=quad*8+j] (W, c-contig rows), B[n=lane&15][k=quad*8+j] (X, needs [p][c]
// -> transpose during staging), D: row(o)=quad*4+reg, col(p)=lane&15.
// The fp32-FMA proj was LDS-BW-bound (1.5-2 B/lane-FMA vs 1.0 balance,
// ~31 us); MFMA moves compute to the matrix pipe -> staging/BW-bound.
__global__ __launch_bounds__(256) void proj(const float* __restrict__ x,
                                            const float* __restrict__ wq,
                                            const float* __restrict__ wk,
                                            const float* __restrict__ wv,
                                            float* __restrict__ q,
                                            float* __restrict__ k,
                                            float* __restrict__ v) {
    __shared__ unsigned short whi[COUT * WPITCH];   // 9 KB
    __shared__ unsigned short wlo[COUT * WPITCH];   // 9 KB
    __shared__ unsigned short xhi[128 * XPITCH];    // 18 KB
    __shared__ unsigned short xlo[128 * XPITCH];    // 18 KB  (total 55.3 KB)

    const int t  = threadIdx.x;
    const int p0 = blockIdx.x * 128;
    const int m  = blockIdx.y;

    const float* __restrict__ wsel = (m == 0) ? wq : (m == 1) ? wk : wv;
    float* __restrict__       osel = (m == 0) ? q  : (m == 1) ? k  : v;

    // ---- stage x: 64c x 128p, float4-coalesced reads, transpose to [p][c]
#pragma unroll
    for (int i = 0; i < 8; ++i) {
        const int f = t + 256 * i;        // 0..2047
        const int c = f >> 5;             // 0..63
        const int j = f & 31;             // p-float4 index
        const float4 val = *(const float4*)(x + c * SP + p0 + j * 4);
        const float vf[4] = { val.x, val.y, val.z, val.w };
#pragma unroll
        for (int e = 0; e < 4; ++e) {
            const int p = j * 4 + e;
            const unsigned short h = f2b(vf[e]);
            const float lof = vf[e] - b2f(h);
            xhi[p * XPITCH + c] = h;
            xlo[p * XPITCH + c] = f2b(lof);
        }
    }
    // ---- stage w: [o][c] direct (c-contiguous), b64 writes
#pragma unroll
    for (int i = 0; i < 4; ++i) {
        const int f  = t + 256 * i;       // 0..1023
        const int o  = f >> 4;
        const int jc = f & 15;
        const float4 val = *(const float4*)(wsel + o * CIN + jc * 4);
        const float vf[4] = { val.x, val.y, val.z, val.w };
        ushort4 h4, l4;
        unsigned short* hp = (unsigned short*)&h4;
        unsigned short* lp = (unsigned short*)&l4;
#pragma unroll
        for (int e = 0; e < 4; ++e) {
            hp[e] = f2b(vf[e]);
            lp[e] = f2b(vf[e] - b2f(hp[e]));
        }
        *(ushort4*)(whi + o * WPITCH + jc * 4) = h4;
        *(ushort4*)(wlo + o * WPITCH + jc * 4) = l4;
    }
    __syncthreads();

    const int wave  = t >> 6;        // 0..3 -> o-quarter
    const int lane  = t & 63;
    const int l15   = lane & 15;
    const int quad  = lane >> 4;
    const int otile = wave * 16;

    // A frags (W): resident across the p-loop
    short8 ahi[2], alo[2];
#pragma unroll
    for (int ks = 0; ks < 2; ++ks) {
        const int off = (otile + l15) * WPITCH + ks * 32 + quad * 8;
        ahi[ks] = *(const short8*)(whi + off);
        alo[ks] = *(const short8*)(wlo + off);
    }

#pragma unroll
    for (int pt = 0; pt < 8; ++pt) {
        const int n = pt * 16 + l15;
        short8 bhi[2], blo[2];
#pragma unroll
        for (int ks = 0; ks < 2; ++ks) {
            const int off = n * XPITCH + ks * 32 + quad * 8;
            bhi[ks] = *(const short8*)(xhi + off);
            blo[ks] = *(const short8*)(xlo + off);
        }
        floatx4 acc = {0.f, 0.f, 0.f, 0.f};
        acc = __builtin_amdgcn_mfma_f32_16x16x32_bf16(ahi[0], bhi[0], acc, 0, 0, 0);
        acc = __builtin_amdgcn_mfma_f32_16x16x32_bf16(ahi[1], bhi[1], acc, 0, 0, 0);
        acc = __builtin_amdgcn_mfma_f32_16x16x32_bf16(ahi[0], blo[0], acc, 0, 0, 0);
        acc = __builtin_amdgcn_mfma_f32_16x16x32_bf16(ahi[1], blo[1], acc, 0, 0, 0);
        acc = __builtin_amdgcn_mfma_f32_16x16x32_bf16(alo[0], bhi[0], acc, 0, 0, 0);
        acc = __builtin_amdgcn_mfma_f32_16x16x32_bf16(alo[1], bhi[1], acc, 0, 0, 0);

        const int p = p0 + pt * 16 + l15;
#pragma unroll
        for (int r = 0; r < 4; ++r) {
            const int o = otile + quad * 4 + r;
            osel[o * SP + p] = acc[r];
        }
    }
}

// DPP shifts within 16-lane rows; bound_ctrl=1 -> out-of-row reads 0 =
// exactly the w-boundary zero-pad (wg==0/15 are DPP row boundaries).
__device__ __forceinline__ float dpp_shr1(float x) {   // lane i <- lane i-1
    return __int_as_float(__builtin_amdgcn_mov_dpp(__float_as_int(x), 0x111, 0xf, 0xf, true));
}
__device__ __forceinline__ float dpp_shl1(float x) {   // lane i <- lane i+1
    return __int_as_float(__builtin_amdgcn_mov_dpp(__float_as_int(x), 0x101, 0xf, 0xf, true));
}

// attn v3 (round-12 measured-best, restored): fully unrolled halo walk,
// compile-time row indices / kd guards, fp32 k AND v tiles (v4's v-bf16
// conversion cost regressed it). exp2 with ql = q*log2e.
template<int AXIS>
__device__ __forceinline__ void attn_tile(const float* __restrict__ kt,
                                          const float* __restrict__ vt,
                                          const float (&ql)[2][4],
                                          float r0, float r1, float r2,
                                          int wg, int h, int dg,
                                          float (&s)[2][4], float (&a)[2][4]) {
#pragma unroll
    for (int nl = 0; nl < 4; ++nl) {             // local halo d-row
#pragma unroll
        for (int kh = 0; kh < 3; ++kh) {
            const int off = ((dg * 2 + nl) * 10 + h + kh) * 64 + wg * 4;
            const float4 km = *(const float4*)(kt + off);
            const float4 vm = *(const float4*)(vt + off);
            const float kl = dpp_shr1(km.w), kr = dpp_shl1(km.x);
            const float vl = dpp_shr1(vm.w), vr = dpp_shl1(vm.x);
            const float krow[6] = { kl, km.x, km.y, km.z, km.w, kr };
            const float vrow[6] = { vl, vm.x, vm.y, vm.z, vm.w, vr };

            const float rkh = (kh == 0) ? r0 : (kh == 1) ? r1 : r2;

#pragma unroll
            for (int di = 0; di < 2; ++di) {
                const int kd = nl - di;          // compile-time
                if (kd >= 0 && kd < 3) {
                    const float rdd = (kd == 0) ? r0 : (kd == 1) ? r1 : r2;
                    const float rr  = (AXIS == 0) ? rdd : (AXIS == 1) ? rkh : 0.f;
#pragma unroll
                    for (int wi = 0; wi < 4; ++wi) {
                        const float qv = ql[di][wi];
#pragma unroll
                        for (int kw = 0; kw < 3; ++kw) {
                            const float rc = (AXIS == 2)
                                           ? ((kw == 0) ? r0 : (kw == 1) ? r1 : r2)
                                           : rr;
                            const float e = __builtin_amdgcn_exp2f(qv * (krow[wi + kw] + rc));
                            s[di][wi] += e;
                            a[di][wi] = fmaf(e, vrow[wi + kw], a[di][wi]);
                        }
                    }
                }
            }
        }
    }
}

__global__ __launch_bounds__(256) void attn(const float* __restrict__ kbuf,
                                            const float* __restrict__ vbuf,
                                            const float* __restrict__ qbuf,
                                            const float* __restrict__ rel_d,
                                            const float* __restrict__ rel_h,
                                            const float* __restrict__ rel_w,
                                            float* __restrict__ out) {
    __shared__ float kt[60 * 64];    // [nn][hp][w], 15 KB
    __shared__ float vt[60 * 64];

    const int dt = blockIdx.x;       // 0..3
    const int ht = blockIdx.y;       // 0..7
    const int o  = blockIdx.z;       // 0..63

    const int d0 = dt * 4;
    const int h0 = ht * 8;
    const int t  = threadIdx.x;

    const float* __restrict__ kc = kbuf + o * SP;
    const float* __restrict__ vc = vbuf + o * SP;

#pragma unroll
    for (int i = 0; i < 8; ++i) {
        const int idx = t + 256 * i;
        if (idx < 1920) {
            const bool isv = idx >= 960;
            const int rem  = isv ? idx - 960 : idx;
            const int row  = rem >> 4;         // 0..59
            const int j    = rem & 15;
            const int nn   = row / 10;
            const int hp   = row - nn * 10;
            const int dpg  = d0 - 1 + nn;
            const int hpg  = h0 - 1 + hp;
            float4 val = make_float4(0.f, 0.f, 0.f, 0.f);
            if ((unsigned)dpg < (unsigned)DD && (unsigned)hpg < (unsigned)HH) {
                const float* src = (isv ? vc : kc) + (dpg * HH + hpg) * WW + j * 4;
                val = *(const float4*)src;
            }
            *(float4*)((isv ? vt : kt) + row * 64 + j * 4) = val;
        }
    }

    const int wg = t & 15;           // 4w each
    const int h  = (t >> 4) & 7;
    const int dg = t >> 7;           // 0/1: d-pair

    float ql[2][4];
#pragma unroll
    for (int di = 0; di < 2; ++di) {
        const int dabs = d0 + dg * 2 + di;
        const float4 q4 = *(const float4*)(qbuf + o * SP + (dabs * HH + (h0 + h)) * WW + wg * 4);
        ql[di][0] = q4.x * LOG2E; ql[di][1] = q4.y * LOG2E;
        ql[di][2] = q4.z * LOG2E; ql[di][3] = q4.w * LOG2E;
    }

    __syncthreads();

    float s[2][4] = {};
    float a[2][4] = {};

    if (o < 21) {
        attn_tile<0>(kt, vt, ql, rel_d[o * 3 + 0], rel_d[o * 3 + 1], rel_d[o * 3 + 2],
                     wg, h, dg, s, a);
    } else if (o < 42) {
        const int b = o - 21;
        attn_tile<1>(kt, vt, ql, rel_h[b * 3 + 0], rel_h[b * 3 + 1], rel_h[b * 3 + 2],
                     wg, h, dg, s, a);
    } else {
        const int b = o - 42;
        attn_tile<2>(kt, vt, ql, rel_w[b * 3 + 0], rel_w[b * 3 + 1], rel_w[b * 3 + 2],
                     wg, h, dg, s, a);
    }

#pragma unroll
    for (int di = 0; di < 2; ++di) {
        const int dabs = d0 + dg * 2 + di;
        float4 ov;
        ov.x = a[di][0] * __builtin_amdgcn_rcpf(s[di][0]);
        ov.y = a[di][1] * __builtin_amdgcn_rcpf(s[di][1]);
        ov.z = a[di][2] * __builtin_amdgcn_rcpf(s[di][2]);
        ov.w = a[di][3] * __builtin_amdgcn_rcpf(s[di][3]);
        *(float4*)(out + o * SP + (dabs * HH + (h0 + h)) * WW + wg * 4) = ov;
    }
}

extern "C" void kernel_launch(void* const* d_in, const int* in_sizes, int n_in,
                              void* d_out, int out_size, void* d_ws, size_t ws_size,
                              hipStream_t stream) {
    const float* x     = (const float*)d_in[0];
    const float* w_q   = (const float*)d_in[1];
    const float* w_k   = (const float*)d_in[2];
    const float* w_v   = (const float*)d_in[3];
    const float* rel_d = (const float*)d_in[4];
    const float* rel_h = (const float*)d_in[5];
    const float* rel_w = (const float*)d_in[6];
    float* out = (float*)d_out;

    float* ws = (float*)d_ws;
    float* q  = ws;
    float* k  = ws + (size_t)COUT * SP;
    float* v  = ws + 2 * (size_t)COUT * SP;

    proj<<<dim3(SP / 128, 3), 256, 0, stream>>>(x, w_q, w_k, w_v, q, k, v);
    attn<<<dim3(4, 8, 64), 256, 0, stream>>>(k, v, q, rel_d, rel_h, rel_w, out);
}